// Round 4
// baseline (187.049 us; speedup 1.0000x reference)
//
#include <hip/hip_runtime.h>

namespace {
constexpr int S = 1024;
constexpr int OFF = 256; // (S-H)/2 = (S-W)/2

typedef float f32x4 __attribute__((ext_vector_type(4)));

// stripe indicator as float {0,1}; exact int div by runtime gb via float
// reciprocal estimate + one-step fixup (identical to all passing rounds)
__device__ __forceinline__ float stripef(int i, int start, int gb, int len, int n, float inv_gb) {
    const int d = i - start;
    int q = (int)((float)d * inv_gb);
    int r = d - q * gb;
    if (r < 0)        { r += gb; --q; }
    else if (r >= gb) { r -= gb; ++q; }
    return (d >= 0 && r < len && q < n) ? 1.0f : 0.0f;
}

// Copy-style rolling pipeline: 2048 blocks x 256 thr; each block owns 3072
// contiguous float4 (48 KB) of one image; 12 float4/thread; prefetch ring of
// depth 4 so every unrolled iteration is {issue 1 load, ~40 VALU mask ops,
// retire 1 store} — the steady-state interleave of the 6.3 TB/s copy µbench,
// instead of the burst-of-6-loads-then-6-stores shape of rounds 0-3.
// Mask arithmetic byte-identical to the passing rounds (separable closed form
// m = cx + ry - cx*ry; reflection provably identity for this angle range).
__global__ __launch_bounds__(256) void gridmask_kernel(
    const float* __restrict__ images,
    const float* __restrict__ angles,
    const int* __restrict__ gridblock,
    const int* __restrict__ start1,
    const int* __restrict__ start2,
    float* __restrict__ out)
{
    __shared__ float2 colsAD[1024];   // {v[i], v[i+1]-v[i]}
    __shared__ float2 rowsAD[1024];

    const int tid = threadIdx.x;
    const int blk = blockIdx.x;          // 2048 blocks
    const int b   = blk >> 6;            // 64 blocks per image
    const int seg = blk & 63;

    const size_t f4base = (size_t)b * 196608 + (size_t)seg * 3072;
    const float4* __restrict__ gin4 = (const float4*)images + f4base;
    f32x4* __restrict__ gout4 = (f32x4*)out + f4base;

    // ---- prime the prefetch ring (4 loads in flight) ----
    float4 p[4];
#pragma unroll
    for (int j = 0; j < 4; ++j) p[j] = gin4[(j << 8) + tid];

    const float ang = angles[b];
    const int gb = gridblock[b];
    const int s1 = start1[b];
    const int s2 = start2[b];

    const float gbf = (float)gb;
    // match numpy's two-step f32 rounding exactly: no FMA contraction
    int len = (int)(__fadd_rn(__fmul_rn(gbf, 0.6f), 0.5f));
    len = min(max(len, 1), gb - 1);
    const int n = S / gb;
    const float inv_gb = 1.0f / gbf;

    {   // LUT build: thread t fills entries 4t..4t+3 of both tables
        const int i0 = tid << 2;
        float rv[5], cv[5];
#pragma unroll
        for (int i = 0; i < 5; ++i) {
            rv[i] = stripef(i0 + i, s1, gb, len, n, inv_gb);
            cv[i] = stripef(i0 + i, s2, gb, len, n, inv_gb);
        }
#pragma unroll
        for (int i = 0; i < 4; ++i) {
            rowsAD[i0 + i] = make_float2(rv[i], rv[i + 1] - rv[i]);
            colsAD[i0 + i] = make_float2(cv[i], cv[i + 1] - cv[i]);
        }
    }
    __syncthreads();

    float sn, cs;
    sincosf(ang, &sn, &cs);
    const float c = (float)(S - 1) * 0.5f;   // 511.5

    const unsigned wbase = ((unsigned)seg * 3072u) << 2;   // within-image float base

#pragma unroll
    for (int k = 0; k < 12; ++k) {
        // grab current, immediately reuse the ring slot for the k+4 prefetch
        const float4 cur = p[k & 3];
        if (k < 8) p[k & 3] = gin4[((k + 4) << 8) + tid];

        const int lf4 = (k << 8) + tid;                     // [0,3072)
        const unsigned wlf = wbase + ((unsigned)lf4 << 2);  // within-image float idx
        const unsigned q = __umulhi(wlf, 0xAAAAAAABu) >> 1; // floor(wlf/3), pixel idx
        const int r = (int)(wlf - q * 3u);

        // inline mask for pixels q and q+1 (q+1 never exceeds the image:
        // last float4 of an image has q = 262142). sx,sy in [154.5, 868.5]
        // for this angle range — reflection is identity, no clamp needed.
        float mm[2];
#pragma unroll
        for (int t2 = 0; t2 < 2; ++t2) {
            const unsigned qq = q + (unsigned)t2;
            const int y = (int)(qq >> 9);
            const int x = (int)(qq & 511u);
            const float X = (float)(x + OFF) - c;
            const float Y = (float)(y + OFF) - c;
            const float sx = cs * X + sn * Y + c;
            const float sy = cs * Y - sn * X + c;
            const float x0f = floorf(sx);
            const float y0f = floorf(sy);
            const float fx = sx - x0f;
            const float fy = sy - y0f;
            const float2 cad = colsAD[(int)x0f];
            const float2 rad = rowsAD[(int)y0f];
            const float cxv = fmaf(fx, cad.y, cad.x);
            const float ryv = fmaf(fy, rad.y, rad.x);
            mm[t2] = cxv + ryv - cxv * ryv;
        }
        const float ma = mm[0], mb = mm[1];
        // component ch belongs to pixel q + ((r+ch) >= 3)
        const float m1 = (r == 2) ? mb : ma;
        const float m2 = (r != 0) ? mb : ma;
        f32x4 o;
        o.x = cur.x * ma;
        o.y = cur.y * m1;
        o.z = cur.z * m2;
        o.w = cur.w * mb;
        gout4[lf4] = o;
    }
}
} // namespace

extern "C" void kernel_launch(void* const* d_in, const int* in_sizes, int n_in,
                              void* d_out, int out_size, void* d_ws, size_t ws_size,
                              hipStream_t stream) {
    const float* images    = (const float*)d_in[0];
    const float* angles    = (const float*)d_in[1];
    const int*   gridblock = (const int*)d_in[2];
    const int*   start1    = (const int*)d_in[3];
    const int*   start2    = (const int*)d_in[4];
    float* outp = (float*)d_out;

    // 2048 blocks x 256 threads; each block: 3072 contiguous float4 of one image
    gridmask_kernel<<<2048, 256, 0, stream>>>(images, angles, gridblock, start1, start2, outp);
}

// Round 5
// 184.605 us; speedup vs baseline: 1.0132x; 1.0132x over previous
//
#include <hip/hip_runtime.h>

namespace {
constexpr int S = 1024;
constexpr int OFF = 256; // (S-H)/2 = (S-W)/2

typedef float f32x4 __attribute__((ext_vector_type(4)));

// stripe indicator as float {0,1}; exact int div by runtime gb via float
// reciprocal estimate + one-step fixup (identical to all passing rounds)
__device__ __forceinline__ float stripef(int i, int start, int gb, int len, int n, float inv_gb) {
    const int d = i - start;
    int q = (int)((float)d * inv_gb);
    int r = d - q * gb;
    if (r < 0)        { r += gb; --q; }
    else if (r >= gb) { r -= gb; ++q; }
    return (d >= 0 && r < len && q < n) ? 1.0f : 0.0f;
}

// Max memory-level parallelism variant: 1024 blocks x 512 thr
//   - 4 blocks/CU x 8 waves = 32 waves/CU = 100% theoretical occupancy
//     (VGPR kept <= 64, LDS 16 KB x 4 = 64 KB)
//   - prefetch ring of 6 float4/thread = 6 KB in flight per wave
//     (~8x round-4's in-flight bytes/CU) to cover HBM read latency per
//     Little's law — the one axis rounds 0-4 never pushed.
//   - nontemporal stores: output is never re-read; keep L3 for the input.
// Mask arithmetic byte-identical to rounds 1-4 (separable closed form
// m = cx + ry - cx*ry; reflection provably identity for this angle range).
__global__ __launch_bounds__(512) void gridmask_kernel(
    const float* __restrict__ images,
    const float* __restrict__ angles,
    const int* __restrict__ gridblock,
    const int* __restrict__ start1,
    const int* __restrict__ start2,
    float* __restrict__ out)
{
    __shared__ float2 colsAD[1024];   // {v[i], v[i+1]-v[i]}
    __shared__ float2 rowsAD[1024];

    const int tid = threadIdx.x;         // 0..511
    const int blk = blockIdx.x;          // 1024 blocks
    const int b   = blk >> 5;            // 32 blocks per image
    const int seg = blk & 31;

    const size_t f4base = (size_t)b * 196608 + (size_t)seg * 6144;
    const float4* __restrict__ gin4 = (const float4*)images + f4base;
    f32x4* __restrict__ gout4 = (f32x4*)out + f4base;

    // ---- prime the prefetch ring: 6 loads (6 KB/wave) in flight ----
    float4 p[6];
#pragma unroll
    for (int j = 0; j < 6; ++j) p[j] = gin4[(j << 9) + tid];

    const float ang = angles[b];
    const int gb = gridblock[b];
    const int s1 = start1[b];
    const int s2 = start2[b];

    const float gbf = (float)gb;
    // match numpy's two-step f32 rounding exactly: no FMA contraction
    int len = (int)(__fadd_rn(__fmul_rn(gbf, 0.6f), 0.5f));
    len = min(max(len, 1), gb - 1);
    const int n = S / gb;
    const float inv_gb = 1.0f / gbf;

    {   // LUT build: thread t fills entries 2t, 2t+1 of both tables
        const int i0 = tid << 1;
        float rv[3], cv[3];
#pragma unroll
        for (int i = 0; i < 3; ++i) {
            rv[i] = stripef(i0 + i, s1, gb, len, n, inv_gb);
            cv[i] = stripef(i0 + i, s2, gb, len, n, inv_gb);
        }
#pragma unroll
        for (int i = 0; i < 2; ++i) {
            rowsAD[i0 + i] = make_float2(rv[i], rv[i + 1] - rv[i]);
            colsAD[i0 + i] = make_float2(cv[i], cv[i + 1] - cv[i]);
        }
    }
    __syncthreads();

    float sn, cs;
    sincosf(ang, &sn, &cs);
    const float c = (float)(S - 1) * 0.5f;   // 511.5

    const unsigned wbase = (unsigned)seg * 24576u;   // within-image float base

#pragma unroll
    for (int k = 0; k < 12; ++k) {
        // take current; immediately refill the ring slot with the k+6 load
        const float4 cur = p[k % 6];
        if (k < 6) p[k % 6] = gin4[((k + 6) << 9) + tid];

        const int lf4 = (k << 9) + tid;                     // [0,6144)
        const unsigned wlf = wbase + ((unsigned)lf4 << 2);  // within-image float idx
        const unsigned q = __umulhi(wlf, 0xAAAAAAABu) >> 1; // floor(wlf/3), pixel idx
        const int r = (int)(wlf - q * 3u);

        // inline mask for pixels q and q+1 (q+1 never exceeds the image:
        // last float4 of an image has q = 262142). sx,sy in [154.5, 868.5]
        // for this angle range — reflection is identity, no clamp needed.
        float mm[2];
#pragma unroll
        for (int t2 = 0; t2 < 2; ++t2) {
            const unsigned qq = q + (unsigned)t2;
            const int y = (int)(qq >> 9);
            const int x = (int)(qq & 511u);
            const float X = (float)(x + OFF) - c;
            const float Y = (float)(y + OFF) - c;
            const float sx = cs * X + sn * Y + c;
            const float sy = cs * Y - sn * X + c;
            const float x0f = floorf(sx);
            const float y0f = floorf(sy);
            const float fx = sx - x0f;
            const float fy = sy - y0f;
            const float2 cad = colsAD[(int)x0f];
            const float2 rad = rowsAD[(int)y0f];
            const float cxv = fmaf(fx, cad.y, cad.x);
            const float ryv = fmaf(fy, rad.y, rad.x);
            mm[t2] = cxv + ryv - cxv * ryv;
        }
        const float ma = mm[0], mb = mm[1];
        // component ch belongs to pixel q + ((r+ch) >= 3)
        const float m1 = (r == 2) ? mb : ma;
        const float m2 = (r != 0) ? mb : ma;
        f32x4 o;
        o.x = cur.x * ma;
        o.y = cur.y * m1;
        o.z = cur.z * m2;
        o.w = cur.w * mb;
        __builtin_nontemporal_store(o, gout4 + lf4);
    }
}
} // namespace

extern "C" void kernel_launch(void* const* d_in, const int* in_sizes, int n_in,
                              void* d_out, int out_size, void* d_ws, size_t ws_size,
                              hipStream_t stream) {
    const float* images    = (const float*)d_in[0];
    const float* angles    = (const float*)d_in[1];
    const int*   gridblock = (const int*)d_in[2];
    const int*   start1    = (const int*)d_in[3];
    const int*   start2    = (const int*)d_in[4];
    float* outp = (float*)d_out;

    // 1024 blocks x 512 threads; each block: 6144 contiguous float4 of one image
    gridmask_kernel<<<1024, 512, 0, stream>>>(images, angles, gridblock, start1, start2, outp);
}